// Round 16
// baseline (2415.964 us; speedup 1.0000x reference)
//
#include <hip/hip_runtime.h>
#include <math.h>

#define E_DIM   1024
#define M_ROWS  4096
#define NKP     320
#define GATES_N 4096
#define MF      (M_ROWS * E_DIM)           // 4,194,304
#define SF      ((size_t)32 * NKP * E_DIM) // 10,485,760
#define AST     328                        // att LDS stride

typedef __attribute__((ext_vector_type(8))) short bf16x8;
typedef __attribute__((ext_vector_type(4))) float f32x4;

// ---- persistent device state ----
__device__ unsigned int   g_Gxp[(size_t)M_ROWS * GATES_N];      // packed 2-split Gx
__device__ float          g_h[MF], g_c[MF], g_r[MF];
__device__ float          g_meanS[32 * E_DIM];                  // rowmean of S per batch
__device__ unsigned short g_hinh[MF], g_hinm[MF], g_hinl[MF];   // 3-split of h+r
__device__ unsigned short g_xh[MF],   g_xm[MF];
__device__ unsigned short g_Wihh[MF], g_Wihm[MF];
__device__ unsigned short g_Whhh[MF], g_Whhm[MF];
__device__ unsigned short g_Sh[SF], g_Sm[SF], g_Sl[SF];         // 3-split S [b][j][k]
__device__ unsigned short g_STh[SF], g_STm[SF];                 // 2-split S^T [b][e][j]

__device__ __forceinline__ unsigned short f2bf(float f) {
    unsigned int u = __builtin_bit_cast(unsigned int, f);
    return (unsigned short)((u + 0x7fffu + ((u >> 16) & 1u)) >> 16);  // RNE
}
__device__ __forceinline__ float bf2f(unsigned short s) {
    unsigned int u = ((unsigned int)s) << 16;
    return __builtin_bit_cast(float, u);
}
__device__ __forceinline__ void split2(float v, unsigned short& hi, unsigned short& mi) {
    hi = f2bf(v); mi = f2bf(v - bf2f(hi));
}
__device__ __forceinline__ void split3(float v, unsigned short& hi, unsigned short& mi,
                                       unsigned short& lo) {
    hi = f2bf(v);
    const float r1 = v - bf2f(hi);
    mi = f2bf(r1);
    lo = f2bf(r1 - bf2f(mi));
}
__device__ __forceinline__ unsigned int pack2(float v) {
    unsigned short hi, mi; split2(v, hi, mi);
    return (unsigned int)hi | ((unsigned int)mi << 16);
}
__device__ __forceinline__ float unpack2(unsigned int u) {
    return bf2f((unsigned short)(u & 0xffffu)) + bf2f((unsigned short)(u >> 16));
}
__device__ __forceinline__ float sigmoid_f(float v) { return 1.f / (1.f + __expf(-v)); }
__device__ __forceinline__ float tanh_f(float v) {
    const float vc = fminf(fmaxf(v, -15.f), 15.f);
    const float t = __expf(2.f * vc);
    return (t - 1.f) / (t + 1.f);
}

// LDS union: GEMM role = dbuf B-only [128][64]-short tiles = 32 KB.
// attn role = 32-row att 2-split + reduce = 43 KB. Union 43 KB.
union SharedU {
    struct { unsigned short B2[2][128 * 64]; } g;
    struct {
        unsigned short ah[32][AST], am[32][AST];
        float red_m[4][32], red_s[4][32];
    } a;
};

// ---------------------------------------------------------------------------
__global__ __launch_bounds__(256) void prep_kernel(
    const float* __restrict__ Wih, const float* __restrict__ Whh,
    const float* __restrict__ x)
{
    const int i = blockIdx.x * 256 + threadIdx.x;   // x4 elements
    const float4 w4 = reinterpret_cast<const float4*>(Wih)[i];
    const float4 v4 = reinterpret_cast<const float4*>(Whh)[i];
    const float4 x4 = reinterpret_cast<const float4*>(x)[i];
    ushort4 ah, am, bh, bm, ch, cm;
    split2(w4.x, ah.x, am.x); split2(w4.y, ah.y, am.y);
    split2(w4.z, ah.z, am.z); split2(w4.w, ah.w, am.w);
    split2(v4.x, bh.x, bm.x); split2(v4.y, bh.y, bm.y);
    split2(v4.z, bh.z, bm.z); split2(v4.w, bh.w, bm.w);
    split2(x4.x, ch.x, cm.x); split2(x4.y, ch.y, cm.y);
    split2(x4.z, ch.z, cm.z); split2(x4.w, ch.w, cm.w);
    reinterpret_cast<ushort4*>(g_Wihh)[i] = ah; reinterpret_cast<ushort4*>(g_Wihm)[i] = am;
    reinterpret_cast<ushort4*>(g_Whhh)[i] = bh; reinterpret_cast<ushort4*>(g_Whhm)[i] = bm;
    reinterpret_cast<ushort4*>(g_xh)[i]   = ch; reinterpret_cast<ushort4*>(g_xm)[i]   = cm;
    const float4 z = make_float4(0.f, 0.f, 0.f, 0.f);
    reinterpret_cast<float4*>(g_h)[i] = z;
    reinterpret_cast<float4*>(g_c)[i] = z;
    reinterpret_cast<float4*>(g_r)[i] = z;
}

// ---------------------------------------------------------------------------
__global__ __launch_bounds__(256) void split_S_kernel(const float* __restrict__ S)
{
    __shared__ float t[64][65];
    const int b = blockIdx.z, j0 = blockIdx.y * 64, k0 = blockIdx.x * 64;
    const float* Sb = S + (size_t)b * NKP * E_DIM;
    const int c = threadIdx.x & 63, r4 = threadIdx.x >> 6;
    #pragma unroll
    for (int i = 0; i < 16; ++i) {
        const int row = r4 * 16 + i;
        const float v = Sb[(size_t)(j0 + row) * E_DIM + k0 + c];
        t[row][c] = v;
        unsigned short hi, mi, lo;
        split3(v, hi, mi, lo);
        const size_t si = (size_t)b * NKP * E_DIM + (size_t)(j0 + row) * E_DIM + k0 + c;
        g_Sh[si] = hi; g_Sm[si] = mi; g_Sl[si] = lo;
    }
    __syncthreads();
    #pragma unroll
    for (int i = 0; i < 16; ++i) {
        const int row = r4 * 16 + i;            // k(embedding)-offset within tile
        const float v = t[c][row];              // = S[j0+c][k0+row]
        unsigned short hi, mi;
        split2(v, hi, mi);
        const size_t sti = (size_t)b * E_DIM * NKP + (size_t)(k0 + row) * NKP + j0 + c;
        g_STh[sti] = hi; g_STm[sti] = mi;
    }
}

// ---------------------------------------------------------------------------
// rowmean of S per batch: g_meanS[b][e] = (1/320) sum_j S[b][j][e]
// ---------------------------------------------------------------------------
__global__ __launch_bounds__(256) void meanS_kernel(const float* __restrict__ S)
{
    const int b = blockIdx.x >> 2;
    const int e = (blockIdx.x & 3) * 256 + threadIdx.x;
    const float* Sb = S + (size_t)b * NKP * E_DIM + e;
    float s = 0.f;
    #pragma unroll 4
    for (int j = 0; j < NKP; ++j) s += Sb[(size_t)j * E_DIM];
    g_meanS[b * E_DIM + e] = s * (1.0f / NKP);
}

// ---------------------------------------------------------------------------
// Degenerate step 0 (carry all-zero): gates = Gx exactly, att uniform ->
// r(1) = meanS[b]. Emits c(1) and 3-split of hin(1) = h(1) + meanS.
// ---------------------------------------------------------------------------
__global__ __launch_bounds__(256) void step0_kernel(const float* __restrict__ x)
{
    const int i = blockIdx.x * 256 + threadIdx.x;   // float4 index over [4096][1024]
    const int row = i >> 8, col4 = i & 255;
    const int b = row >> 7;
    const float4 m4 = reinterpret_cast<const float4*>(g_meanS)[b * 256 + col4];
    const float4 x4 = reinterpret_cast<const float4*>(x)[i];
    const uint4 gi4 = reinterpret_cast<const uint4*>(g_Gxp)[row * 1024 + col4];
    const uint4 gg4 = reinterpret_cast<const uint4*>(g_Gxp)[row * 1024 + 512 + col4];
    const uint4 go4 = reinterpret_cast<const uint4*>(g_Gxp)[row * 1024 + 768 + col4];
    float4 c4, hin4;
    {
        const float c0 = sigmoid_f(unpack2(gi4.x)) * tanh_f(unpack2(gg4.x));
        const float c1 = sigmoid_f(unpack2(gi4.y)) * tanh_f(unpack2(gg4.y));
        const float c2 = sigmoid_f(unpack2(gi4.z)) * tanh_f(unpack2(gg4.z));
        const float c3 = sigmoid_f(unpack2(gi4.w)) * tanh_f(unpack2(gg4.w));
        c4 = make_float4(c0, c1, c2, c3);
        hin4.x = sigmoid_f(unpack2(go4.x)) * tanh_f(c0) + x4.x + m4.x;
        hin4.y = sigmoid_f(unpack2(go4.y)) * tanh_f(c1) + x4.y + m4.y;
        hin4.z = sigmoid_f(unpack2(go4.z)) * tanh_f(c2) + x4.z + m4.z;
        hin4.w = sigmoid_f(unpack2(go4.w)) * tanh_f(c3) + x4.w + m4.w;
    }
    reinterpret_cast<float4*>(g_c)[i] = c4;
    ushort4 oh, om, ol;
    split3(hin4.x, oh.x, om.x, ol.x);
    split3(hin4.y, oh.y, om.y, ol.y);
    split3(hin4.z, oh.z, om.z, ol.z);
    split3(hin4.w, oh.w, om.w, ol.w);
    reinterpret_cast<ushort4*>(g_hinh)[i] = oh;
    reinterpret_cast<ushort4*>(g_hinm)[i] = om;
    reinterpret_cast<ushort4*>(g_hinl)[i] = ol;
}

// ---------------------------------------------------------------------------
__global__ __launch_bounds__(256) void add_split3_kernel()
{
    const int i = blockIdx.x * 256 + threadIdx.x;
    const float4 a = reinterpret_cast<const float4*>(g_h)[i];
    const float4 b = reinterpret_cast<const float4*>(g_r)[i];
    ushort4 oh, om, ol;
    split3(a.x + b.x, oh.x, om.x, ol.x);
    split3(a.y + b.y, oh.y, om.y, ol.y);
    split3(a.z + b.z, oh.z, om.z, ol.z);
    split3(a.w + b.w, oh.w, om.w, ol.w);
    reinterpret_cast<ushort4*>(g_hinh)[i] = oh;
    reinterpret_cast<ushort4*>(g_hinm)[i] = om;
    reinterpret_cast<ushort4*>(g_hinl)[i] = ol;
}

// ---------------------------------------------------------------------------
// Gx = x @ Wih^T + biases (packed 2-split out). Dbuf K-loop, counted vmcnt.
// (Round-15 version, runs once.)
// ---------------------------------------------------------------------------
__global__ __launch_bounds__(256, 2) void gemm_gx_kernel(
    const float* __restrict__ bih, const float* __restrict__ bhh)
{
    __shared__ struct { unsigned short A2[2][128 * 64]; unsigned short B2[2][128 * 64]; } sh;
    const int tid = threadIdx.x, l = tid & 63, w = tid >> 6;
    const int b15 = l & 15, lg = l >> 4, x7 = b15 & 7;
    const int d = blockIdx.x;
    const int j = d >> 3;
    const int row0 = (j >> 2) * 128, e0 = ((d & 7) * 4 + (j & 3)) * 32;
    const int arow = w * 32 + b15;
    f32x4 acc[2][8] = {};

    auto stage = [&](int bf, int kt) {
        #pragma unroll
        for (int it = 0; it < 4; ++it) {
            const int slot = it * 256 + tid;
            const int row  = slot >> 3;
            const int chs  = (slot & 7) ^ (row & 7);
            const int kb   = (chs & 3) * 8;
            const unsigned short* sA = (chs & 4) ? g_xm   : g_xh;
            const unsigned short* sB = (chs & 4) ? g_Wihm : g_Wihh;
            const int ldsoff = bf * 16384 + slot * 16;
            const size_t aidx = (size_t)(row0 + row) * E_DIM + kt + kb;
            const int gt = row >> 5, er = row & 31;
            const size_t bidx = (size_t)(gt * E_DIM + e0 + er) * E_DIM + kt + kb;
            __builtin_amdgcn_global_load_lds(
                (const __attribute__((address_space(1))) void*)&sA[aidx],
                (__attribute__((address_space(3))) void*)((char*)sh.A2 + ldsoff), 16, 0, 0);
            __builtin_amdgcn_global_load_lds(
                (const __attribute__((address_space(1))) void*)&sB[bidx],
                (__attribute__((address_space(3))) void*)((char*)sh.B2 + ldsoff), 16, 0, 0);
        }
    };

    stage(0, 0);
    int cur = 0;
    for (int kt = 0; kt < E_DIM; kt += 32) {
        if (kt + 32 < E_DIM) {
            stage(cur ^ 1, kt + 32);
            asm volatile("s_waitcnt vmcnt(8)" ::: "memory");
        } else {
            asm volatile("s_waitcnt vmcnt(0)" ::: "memory");
        }
        __builtin_amdgcn_sched_barrier(0);
        __builtin_amdgcn_s_barrier();
        __builtin_amdgcn_sched_barrier(0);
        const unsigned short* Ab = sh.A2[cur];
        const unsigned short* Bb = sh.B2[cur];
        bf16x8 avh[2], avm[2];
        #pragma unroll
        for (int m = 0; m < 2; ++m) {
            const int rr = arow + m * 16;
            avh[m] = *reinterpret_cast<const bf16x8*>(&Ab[rr * 64 + ((lg ^ x7) * 8)]);
            avm[m] = *reinterpret_cast<const bf16x8*>(&Ab[rr * 64 + (((4 | lg) ^ x7) * 8)]);
        }
        #pragma unroll
        for (int n = 0; n < 8; ++n) {
            const int br = n * 16 + b15;
            const bf16x8 bvh = *reinterpret_cast<const bf16x8*>(&Bb[br * 64 + ((lg ^ x7) * 8)]);
            const bf16x8 bvm = *reinterpret_cast<const bf16x8*>(&Bb[br * 64 + (((4 | lg) ^ x7) * 8)]);
            #pragma unroll
            for (int m = 0; m < 2; ++m) {
                acc[m][n] = __builtin_amdgcn_mfma_f32_16x16x32_bf16(avh[m], bvm, acc[m][n], 0, 0, 0);
                acc[m][n] = __builtin_amdgcn_mfma_f32_16x16x32_bf16(avm[m], bvh, acc[m][n], 0, 0, 0);
                acc[m][n] = __builtin_amdgcn_mfma_f32_16x16x32_bf16(avh[m], bvh, acc[m][n], 0, 0, 0);
            }
        }
        __builtin_amdgcn_sched_barrier(0);
        __builtin_amdgcn_s_barrier();
        __builtin_amdgcn_sched_barrier(0);
        cur ^= 1;
    }

    const int rbase = row0 + w * 32 + lg * 4;
    #pragma unroll
    for (int m = 0; m < 2; ++m)
        #pragma unroll
        for (int n = 0; n < 8; ++n) {
            const int col = n * 16 + b15;
            const int gcol = (col >> 5) * E_DIM + e0 + (col & 31);
            const float add = bih[gcol] + bhh[gcol];
            #pragma unroll
            for (int q = 0; q < 4; ++q)
                __builtin_nontemporal_store(pack2(acc[m][n][q] + add),
                    &g_Gxp[(size_t)(rbase + m * 16 + q) * GATES_N + gcol]);
        }
}

// ---------------------------------------------------------------------------
// Merged step. Blocks 0..127: attention (unchanged, round-10 structure).
// Blocks 128..1151: GEMM+LSTM with A-in-REGISTERS (per-wave rows, global->reg,
// 1-iter ping-pong prefetch) and B-only LDS dbuf with counted vmcnt(8).
// LDS 43 KB union + VGPR ~150 -> target 3 blocks/CU.
// ---------------------------------------------------------------------------
__global__ __launch_bounds__(256) void step_kernel(
    const float* __restrict__ x, float* __restrict__ outp, const int step)
{
    __shared__ SharedU sh;
    const int tid = threadIdx.x, l = tid & 63, w = tid >> 6;
    const int b15 = l & 15, lg = l >> 4, x7 = b15 & 7;

    if (blockIdx.x < 128) {
        // ================= attention role =================
        if (step == 7) return;                          // final r is dead
        const int d = blockIdx.x;
        const int i = d >> 3;
        const int batch = (d & 7) * 4 + (i >> 2), chunk = i & 3;
        const int rowbase = batch * 128 + chunk * 32;
        const size_t sbase  = (size_t)batch * NKP * E_DIM;
        const size_t stbase = (size_t)batch * E_DIM * NKP;

        f32x4 qacc[2][5] = {};
        for (int kt = 0; kt < E_DIM; kt += 32) {
            bf16x8 qh[2], qm[2], ql[2];
            #pragma unroll
            for (int m = 0; m < 2; ++m) {
                const size_t qi = (size_t)(rowbase + m * 16 + b15) * E_DIM + kt + lg * 8;
                qh[m] = *reinterpret_cast<const bf16x8*>(&g_hinh[qi]);
                qm[m] = *reinterpret_cast<const bf16x8*>(&g_hinm[qi]);
                ql[m] = *reinterpret_cast<const bf16x8*>(&g_hinl[qi]);
            }
            #pragma unroll
            for (int n = 0; n < 5; ++n) {
                const size_t si = sbase + (size_t)(w * 80 + n * 16 + b15) * E_DIM + kt + lg * 8;
                const bf16x8 svh = *reinterpret_cast<const bf16x8*>(&g_Sh[si]);
                const bf16x8 svm = *reinterpret_cast<const bf16x8*>(&g_Sm[si]);
                const bf16x8 svl = *reinterpret_cast<const bf16x8*>(&g_Sl[si]);
                #pragma unroll
                for (int m = 0; m < 2; ++m) {
                    f32x4 a = qacc[m][n];
                    a = __builtin_amdgcn_mfma_f32_16x16x32_bf16(qh[m], svl, a, 0, 0, 0);
                    a = __builtin_amdgcn_mfma_f32_16x16x32_bf16(ql[m], svh, a, 0, 0, 0);
                    a = __builtin_amdgcn_mfma_f32_16x16x32_bf16(qm[m], svm, a, 0, 0, 0);
                    a = __builtin_amdgcn_mfma_f32_16x16x32_bf16(qh[m], svm, a, 0, 0, 0);
                    a = __builtin_amdgcn_mfma_f32_16x16x32_bf16(qm[m], svh, a, 0, 0, 0);
                    a = __builtin_amdgcn_mfma_f32_16x16x32_bf16(qh[m], svh, a, 0, 0, 0);
                    qacc[m][n] = a;
                }
            }
        }

        #pragma unroll
        for (int m = 0; m < 2; ++m)
            #pragma unroll
            for (int q = 0; q < 4; ++q) {
                float m0 = qacc[m][0][q];
                #pragma unroll
                for (int n = 1; n < 5; ++n) m0 = fmaxf(m0, qacc[m][n][q]);
                #pragma unroll
                for (int mk = 1; mk < 16; mk <<= 1) m0 = fmaxf(m0, __shfl_xor(m0, mk));
                if (b15 == 0) sh.a.red_m[w][m * 16 + lg * 4 + q] = m0;
            }
        __syncthreads();
        #pragma unroll
        for (int m = 0; m < 2; ++m)
            #pragma unroll
            for (int q = 0; q < 4; ++q) {
                const int row = m * 16 + lg * 4 + q;
                const float gm = fmaxf(fmaxf(sh.a.red_m[0][row], sh.a.red_m[1][row]),
                                       fmaxf(sh.a.red_m[2][row], sh.a.red_m[3][row]));
                float s = 0.f;
                #pragma unroll
                for (int n = 0; n < 5; ++n) {
                    const float e = __expf(qacc[m][n][q] - gm);
                    qacc[m][n][q] = e;
                    s += e;
                }
                #pragma unroll
                for (int mk = 1; mk < 16; mk <<= 1) s += __shfl_xor(s, mk);
                if (b15 == 0) sh.a.red_s[w][row] = s;
            }
        __syncthreads();
        #pragma unroll
        for (int m = 0; m < 2; ++m)
            #pragma unroll
            for (int q = 0; q < 4; ++q) {
                const int row = m * 16 + lg * 4 + q;
                const float inv = 1.f / (sh.a.red_s[0][row] + sh.a.red_s[1][row] +
                                         sh.a.red_s[2][row] + sh.a.red_s[3][row]);
                #pragma unroll
                for (int n = 0; n < 5; ++n) {
                    const float a = qacc[m][n][q] * inv;
                    unsigned short hi, mi;
                    split2(a, hi, mi);
                    const int col = w * 80 + n * 16 + b15;
                    sh.a.ah[row][col] = hi;
                    sh.a.am[row][col] = mi;
                }
            }
        __syncthreads();

        #pragma unroll 1
        for (int pass = 0; pass < 4; ++pass) {
            const int ebase = w * 256 + pass * 64;
            f32x4 pacc[2][4] = {};
            for (int jt = 0; jt < NKP; jt += 32) {
                bf16x8 pah[2], pam[2];
                #pragma unroll
                for (int m = 0; m < 2; ++m) {
                    pah[m] = *reinterpret_cast<const bf16x8*>(&sh.a.ah[m * 16 + b15][jt + lg * 8]);
                    pam[m] = *reinterpret_cast<const bf16x8*>(&sh.a.am[m * 16 + b15][jt + lg * 8]);
                }
                #pragma unroll
                for (int n = 0; n < 4; ++n) {
                    const size_t sti = stbase + (size_t)(ebase + n * 16 + b15) * NKP + jt + lg * 8;
                    const bf16x8 sth = *reinterpret_cast<const bf16x8*>(&g_STh[sti]);
                    const bf16x8 stm = *reinterpret_cast<const bf16x8*>(&g_STm[sti]);
                    #pragma unroll
                    for (int m = 0; m < 2; ++m) {
                        f32x4 a = pacc[m][n];
                        a = __builtin_amdgcn_mfma_f32_16x16x32_bf16(pah[m], stm, a, 0, 0, 0);
                        a = __builtin_amdgcn_mfma_f32_16x16x32_bf16(pam[m], sth, a, 0, 0, 0);
                        a = __builtin_amdgcn_mfma_f32_16x16x32_bf16(pah[m], sth, a, 0, 0, 0);
                        pacc[m][n] = a;
                    }
                }
            }
            #pragma unroll
            for (int m = 0; m < 2; ++m)
                #pragma unroll
                for (int n = 0; n < 4; ++n)
                    #pragma unroll
                    for (int q = 0; q < 4; ++q)
                        __builtin_nontemporal_store(pacc[m][n][q],
                            &g_r[(size_t)(rowbase + m * 16 + lg * 4 + q) * E_DIM +
                                 ebase + n * 16 + b15]);
        }
        return;
    }

    // ========== GEMM + LSTM role: A in registers, B-only LDS dbuf ==========
    const int d2 = blockIdx.x - 128;
    const int j = d2 >> 3;
    const int row0 = (j >> 2) * 128, e0 = ((d2 & 7) * 4 + (j & 3)) * 32;
    const int arow = row0 + w * 32 + b15;           // this wave's A rows (global)
    f32x4 acc[2][8] = {};

    auto stageB = [&](int bf, int kt) {
        #pragma unroll
        for (int it = 0; it < 4; ++it) {
            const int slot = it * 256 + tid;        // 0..1023
            const int row  = slot >> 3;
            const int chs  = (slot & 7) ^ (row & 7);
            const int kb   = (chs & 3) * 8;
            const unsigned short* sB = (chs & 4) ? g_Whhm : g_Whhh;
            const int ldsoff = bf * 16384 + slot * 16;
            const int gt = row >> 5, er = row & 31;
            const size_t bidx = (size_t)(gt * E_DIM + e0 + er) * E_DIM + kt + kb;
            __builtin_amdgcn_global_load_lds(
                (const __attribute__((address_space(1))) void*)&sB[bidx],
                (__attribute__((address_space(3))) void*)((char*)sh.g.B2 + ldsoff), 16, 0, 0);
        }
    };
    auto loadA = [&](bf16x8 (&ah)[2], bf16x8 (&am)[2], int kt) {
        #pragma unroll
        for (int m = 0; m < 2; ++m) {
            const size_t ai = (size_t)(arow + m * 16) * E_DIM + kt + lg * 8;
            ah[m] = *reinterpret_cast<const bf16x8*>(&g_hinh[ai]);
            am[m] = *reinterpret_cast<const bf16x8*>(&g_hinm[ai]);
        }
    };
    auto compute = [&](const bf16x8 (&ah)[2], const bf16x8 (&am)[2], int cur) {
        const unsigned short* Bb = sh.g.B2[cur];
        #pragma unroll
        for (int n = 0; n < 8; ++n) {
            const int br = n * 16 + b15;
            const bf16x8 bvh = *reinterpret_cast<const bf16x8*>(&Bb[br * 64 + ((lg ^ x7) * 8)]);
            const bf16x8 bvm = *reinterpret_cast<const bf16x8*>(&Bb[br * 64 + (((4 | lg) ^ x7) * 8)]);
            #pragma unroll
            for (int m = 0; m < 2; ++m) {
                acc[m][n] = __builtin_amdgcn_mfma_f32_16x16x32_bf16(ah[m], bvm, acc[m][n], 0, 0, 0);
                acc[m][n] = __builtin_amdgcn_mfma_f32_16x16x32_bf16(am[m], bvh, acc[m][n], 0, 0, 0);
                acc[m][n] = __builtin_amdgcn_mfma_f32_16x16x32_bf16(ah[m], bvh, acc[m][n], 0, 0, 0);
            }
        }
    };

    bf16x8 a0h[2], a0m[2], a1h[2], a1m[2];
    stageB(0, 0);
    loadA(a0h, a0m, 0);
    // iter body as macro-lambda; 2x-unrolled k-loop for static regset names.
    // queue at compute k: [B_k(4), A_k(4), B_{k+1}(4), A_{k+1}(4)] -> vmcnt(8).
    #pragma unroll 1
    for (int k2 = 0; k2 < 32; k2 += 2) {
        // --- even iter: uses a0, prefetches a1 ---
        {
            const int k = k2;
            if (k + 1 < 32) {
                stageB((k + 1) & 1, (k + 1) * 32);
                loadA(a1h, a1m, (k + 1) * 32);
                asm volatile("s_waitcnt vmcnt(8)" ::: "memory");
            } else {
                asm volatile("s_waitcnt vmcnt(0)" ::: "memory");
            }
            __builtin_amdgcn_sched_barrier(0);
            __builtin_amdgcn_s_barrier();                  // B buf[k&1] ready
            __builtin_amdgcn_sched_barrier(0);
            compute(a0h, a0m, k & 1);
            __builtin_amdgcn_sched_barrier(0);
            __builtin_amdgcn_s_barrier();                  // WAR on B buf
            __builtin_amdgcn_sched_barrier(0);
        }
        // --- odd iter: uses a1, prefetches a0 ---
        {
            const int k = k2 + 1;
            if (k + 1 < 32) {
                stageB((k + 1) & 1, (k + 1) * 32);
                loadA(a0h, a0m, (k + 1) * 32);
                asm volatile("s_waitcnt vmcnt(8)" ::: "memory");
            } else {
                asm volatile("s_waitcnt vmcnt(0)" ::: "memory");
            }
            __builtin_amdgcn_sched_barrier(0);
            __builtin_amdgcn_s_barrier();
            __builtin_amdgcn_sched_barrier(0);
            compute(a1h, a1m, k & 1);
            __builtin_amdgcn_sched_barrier(0);
            __builtin_amdgcn_s_barrier();
            __builtin_amdgcn_sched_barrier(0);
        }
    }

    const int rbase = row0 + w * 32 + lg * 4;
    const int do_out = (step == 7);
    #pragma unroll
    for (int m = 0; m < 2; ++m)
        #pragma unroll
        for (int er16 = 0; er16 < 2; ++er16) {
            const int e = e0 + er16 * 16 + b15;
            #pragma unroll
            for (int q = 0; q < 4; ++q) {
                const int row = rbase + m * 16 + q;
                const size_t gb = (size_t)row * GATES_N + e;
                const float gi = acc[m][0 + er16][q] + unpack2(__builtin_nontemporal_load(&g_Gxp[gb]));
                const float gf = acc[m][2 + er16][q] + unpack2(__builtin_nontemporal_load(&g_Gxp[gb + E_DIM]));
                const float gg = acc[m][4 + er16][q] + unpack2(__builtin_nontemporal_load(&g_Gxp[gb + 2 * E_DIM]));
                const float go = acc[m][6 + er16][q] + unpack2(__builtin_nontemporal_load(&g_Gxp[gb + 3 * E_DIM]));
                const size_t he = (size_t)row * E_DIM + e;
                const float cn = sigmoid_f(gf) * __builtin_nontemporal_load(&g_c[he]) +
                                 sigmoid_f(gi) * tanh_f(gg);
                const float hn = sigmoid_f(go) * tanh_f(cn) + x[he];
                if (do_out) {
                    __builtin_nontemporal_store(hn, &outp[he]);   // h/c dead after
                } else {
                    __builtin_nontemporal_store(cn, &g_c[he]);
                    g_h[he] = hn;
                }
            }
        }
}

extern "C" void kernel_launch(void* const* d_in, const int* in_sizes, int n_in,
                              void* d_out, int out_size, void* d_ws, size_t ws_size,
                              hipStream_t stream) {
    const float* x   = (const float*)d_in[0];
    const float* sup = (const float*)d_in[1];
    const float* Wih = (const float*)d_in[2];
    const float* Whh = (const float*)d_in[3];
    const float* bih = (const float*)d_in[4];
    const float* bhh = (const float*)d_in[5];
    float* out = (float*)d_out;

    prep_kernel<<<4096, 256, 0, stream>>>(Wih, Whh, x);
    split_S_kernel<<<dim3(16, 5, 32), 256, 0, stream>>>(sup);
    gemm_gx_kernel<<<1024, 256, 0, stream>>>(bih, bhh);
    meanS_kernel<<<128, 256, 0, stream>>>(sup);

    // step 0 is degenerate (zero carry): gates = Gx, attention exactly uniform.
    step0_kernel<<<4096, 256, 0, stream>>>(x);

    for (int s = 1; s < 8; ++s) {
        step_kernel<<<1152, 256, 0, stream>>>(x, out, s);
        if (s < 7) add_split3_kernel<<<4096, 256, 0, stream>>>();
    }
}

// Round 17
// 1903.332 us; speedup vs baseline: 1.2693x; 1.2693x over previous
//
#include <hip/hip_runtime.h>
#include <math.h>

#define E_DIM   1024
#define M_ROWS  4096
#define NKP     320
#define GATES_N 4096
#define MF      (M_ROWS * E_DIM)           // 4,194,304
#define SF      ((size_t)32 * NKP * E_DIM) // 10,485,760
#define AST     328                        // att LDS stride

typedef __attribute__((ext_vector_type(8))) short bf16x8;
typedef __attribute__((ext_vector_type(4))) float f32x4;

// ---- persistent device state ----
__device__ unsigned int   g_Gxp[(size_t)M_ROWS * GATES_N];      // packed 2-split Gx
__device__ float          g_h[MF], g_c[MF], g_r[MF];
__device__ float          g_meanS[32 * E_DIM];                  // rowmean of S per batch
__device__ unsigned short g_hinh[MF], g_hinm[MF], g_hinl[MF];   // 3-split of h+r
__device__ unsigned short g_xh[MF],   g_xm[MF];
__device__ unsigned short g_Wihh[MF], g_Wihm[MF];
__device__ unsigned short g_Whhh[MF], g_Whhm[MF];
__device__ unsigned short g_Sh[SF], g_Sm[SF], g_Sl[SF];         // 3-split S [b][j][k]
__device__ unsigned short g_STh[SF], g_STm[SF];                 // 2-split S^T [b][e][j]

__device__ __forceinline__ unsigned short f2bf(float f) {
    unsigned int u = __builtin_bit_cast(unsigned int, f);
    return (unsigned short)((u + 0x7fffu + ((u >> 16) & 1u)) >> 16);  // RNE
}
__device__ __forceinline__ float bf2f(unsigned short s) {
    unsigned int u = ((unsigned int)s) << 16;
    return __builtin_bit_cast(float, u);
}
__device__ __forceinline__ void split2(float v, unsigned short& hi, unsigned short& mi) {
    hi = f2bf(v); mi = f2bf(v - bf2f(hi));
}
__device__ __forceinline__ void split3(float v, unsigned short& hi, unsigned short& mi,
                                       unsigned short& lo) {
    hi = f2bf(v);
    const float r1 = v - bf2f(hi);
    mi = f2bf(r1);
    lo = f2bf(r1 - bf2f(mi));
}
__device__ __forceinline__ unsigned int pack2(float v) {
    unsigned short hi, mi; split2(v, hi, mi);
    return (unsigned int)hi | ((unsigned int)mi << 16);
}
__device__ __forceinline__ float unpack2(unsigned int u) {
    return bf2f((unsigned short)(u & 0xffffu)) + bf2f((unsigned short)(u >> 16));
}
__device__ __forceinline__ float sigmoid_f(float v) { return 1.f / (1.f + __expf(-v)); }
__device__ __forceinline__ float tanh_f(float v) {
    const float vc = fminf(fmaxf(v, -15.f), 15.f);
    const float t = __expf(2.f * vc);
    return (t - 1.f) / (t + 1.f);
}

// LDS union: GEMM role = dbuf [128][64]-short A/B tiles = 64 KB -> 2 blk/CU.
// attn role = 32-row att 2-split + reduce = 43 KB.
union SharedU {
    struct { unsigned short A2[2][128 * 64]; unsigned short B2[2][128 * 64]; } g;
    struct {
        unsigned short ah[32][AST], am[32][AST];
        float red_m[4][32], red_s[4][32];
    } a;
};

// ---------------------------------------------------------------------------
__global__ __launch_bounds__(256) void prep_kernel(
    const float* __restrict__ Wih, const float* __restrict__ Whh,
    const float* __restrict__ x)
{
    const int i = blockIdx.x * 256 + threadIdx.x;   // x4 elements
    const float4 w4 = reinterpret_cast<const float4*>(Wih)[i];
    const float4 v4 = reinterpret_cast<const float4*>(Whh)[i];
    const float4 x4 = reinterpret_cast<const float4*>(x)[i];
    ushort4 ah, am, bh, bm, ch, cm;
    split2(w4.x, ah.x, am.x); split2(w4.y, ah.y, am.y);
    split2(w4.z, ah.z, am.z); split2(w4.w, ah.w, am.w);
    split2(v4.x, bh.x, bm.x); split2(v4.y, bh.y, bm.y);
    split2(v4.z, bh.z, bm.z); split2(v4.w, bh.w, bm.w);
    split2(x4.x, ch.x, cm.x); split2(x4.y, ch.y, cm.y);
    split2(x4.z, ch.z, cm.z); split2(x4.w, ch.w, cm.w);
    reinterpret_cast<ushort4*>(g_Wihh)[i] = ah; reinterpret_cast<ushort4*>(g_Wihm)[i] = am;
    reinterpret_cast<ushort4*>(g_Whhh)[i] = bh; reinterpret_cast<ushort4*>(g_Whhm)[i] = bm;
    reinterpret_cast<ushort4*>(g_xh)[i]   = ch; reinterpret_cast<ushort4*>(g_xm)[i]   = cm;
    const float4 z = make_float4(0.f, 0.f, 0.f, 0.f);
    reinterpret_cast<float4*>(g_h)[i] = z;
    reinterpret_cast<float4*>(g_c)[i] = z;
    reinterpret_cast<float4*>(g_r)[i] = z;
}

// ---------------------------------------------------------------------------
__global__ __launch_bounds__(256) void split_S_kernel(const float* __restrict__ S)
{
    __shared__ float t[64][65];
    const int b = blockIdx.z, j0 = blockIdx.y * 64, k0 = blockIdx.x * 64;
    const float* Sb = S + (size_t)b * NKP * E_DIM;
    const int c = threadIdx.x & 63, r4 = threadIdx.x >> 6;
    #pragma unroll
    for (int i = 0; i < 16; ++i) {
        const int row = r4 * 16 + i;
        const float v = Sb[(size_t)(j0 + row) * E_DIM + k0 + c];
        t[row][c] = v;
        unsigned short hi, mi, lo;
        split3(v, hi, mi, lo);
        const size_t si = (size_t)b * NKP * E_DIM + (size_t)(j0 + row) * E_DIM + k0 + c;
        g_Sh[si] = hi; g_Sm[si] = mi; g_Sl[si] = lo;
    }
    __syncthreads();
    #pragma unroll
    for (int i = 0; i < 16; ++i) {
        const int row = r4 * 16 + i;            // k(embedding)-offset within tile
        const float v = t[c][row];              // = S[j0+c][k0+row]
        unsigned short hi, mi;
        split2(v, hi, mi);
        const size_t sti = (size_t)b * E_DIM * NKP + (size_t)(k0 + row) * NKP + j0 + c;
        g_STh[sti] = hi; g_STm[sti] = mi;
    }
}

// ---------------------------------------------------------------------------
// rowmean of S per batch: g_meanS[b][e] = (1/320) sum_j S[b][j][e]
// ---------------------------------------------------------------------------
__global__ __launch_bounds__(256) void meanS_kernel(const float* __restrict__ S)
{
    const int b = blockIdx.x >> 2;
    const int e = (blockIdx.x & 3) * 256 + threadIdx.x;
    const float* Sb = S + (size_t)b * NKP * E_DIM + e;
    float s = 0.f;
    #pragma unroll 4
    for (int j = 0; j < NKP; ++j) s += Sb[(size_t)j * E_DIM];
    g_meanS[b * E_DIM + e] = s * (1.0f / NKP);
}

// ---------------------------------------------------------------------------
// Degenerate step 0 (carry all-zero): gates = Gx exactly, att uniform ->
// r(1) = meanS[b]. Emits c(1) and 3-split of hin(1) = h(1) + meanS.
// ---------------------------------------------------------------------------
__global__ __launch_bounds__(256) void step0_kernel(const float* __restrict__ x)
{
    const int i = blockIdx.x * 256 + threadIdx.x;   // float4 index over [4096][1024]
    const int row = i >> 8, col4 = i & 255;
    const int b = row >> 7;
    const float4 m4 = reinterpret_cast<const float4*>(g_meanS)[b * 256 + col4];
    const float4 x4 = reinterpret_cast<const float4*>(x)[i];
    const uint4 gi4 = reinterpret_cast<const uint4*>(g_Gxp)[row * 1024 + col4];
    const uint4 gg4 = reinterpret_cast<const uint4*>(g_Gxp)[row * 1024 + 512 + col4];
    const uint4 go4 = reinterpret_cast<const uint4*>(g_Gxp)[row * 1024 + 768 + col4];
    float4 c4, hin4;
    {
        const float c0 = sigmoid_f(unpack2(gi4.x)) * tanh_f(unpack2(gg4.x));
        const float c1 = sigmoid_f(unpack2(gi4.y)) * tanh_f(unpack2(gg4.y));
        const float c2 = sigmoid_f(unpack2(gi4.z)) * tanh_f(unpack2(gg4.z));
        const float c3 = sigmoid_f(unpack2(gi4.w)) * tanh_f(unpack2(gg4.w));
        c4 = make_float4(c0, c1, c2, c3);
        hin4.x = sigmoid_f(unpack2(go4.x)) * tanh_f(c0) + x4.x + m4.x;
        hin4.y = sigmoid_f(unpack2(go4.y)) * tanh_f(c1) + x4.y + m4.y;
        hin4.z = sigmoid_f(unpack2(go4.z)) * tanh_f(c2) + x4.z + m4.z;
        hin4.w = sigmoid_f(unpack2(go4.w)) * tanh_f(c3) + x4.w + m4.w;
    }
    reinterpret_cast<float4*>(g_c)[i] = c4;
    ushort4 oh, om, ol;
    split3(hin4.x, oh.x, om.x, ol.x);
    split3(hin4.y, oh.y, om.y, ol.y);
    split3(hin4.z, oh.z, om.z, ol.z);
    split3(hin4.w, oh.w, om.w, ol.w);
    reinterpret_cast<ushort4*>(g_hinh)[i] = oh;
    reinterpret_cast<ushort4*>(g_hinm)[i] = om;
    reinterpret_cast<ushort4*>(g_hinl)[i] = ol;
}

// ---------------------------------------------------------------------------
__global__ __launch_bounds__(256) void add_split3_kernel()
{
    const int i = blockIdx.x * 256 + threadIdx.x;
    const float4 a = reinterpret_cast<const float4*>(g_h)[i];
    const float4 b = reinterpret_cast<const float4*>(g_r)[i];
    ushort4 oh, om, ol;
    split3(a.x + b.x, oh.x, om.x, ol.x);
    split3(a.y + b.y, oh.y, om.y, ol.y);
    split3(a.z + b.z, oh.z, om.z, ol.z);
    split3(a.w + b.w, oh.w, om.w, ol.w);
    reinterpret_cast<ushort4*>(g_hinh)[i] = oh;
    reinterpret_cast<ushort4*>(g_hinm)[i] = om;
    reinterpret_cast<ushort4*>(g_hinl)[i] = ol;
}

// ---------------------------------------------------------------------------
// Gx = x @ Wih^T + biases (packed 2-split out). Dbuf K-loop, counted vmcnt.
// ---------------------------------------------------------------------------
__global__ __launch_bounds__(256, 2) void gemm_gx_kernel(
    const float* __restrict__ bih, const float* __restrict__ bhh)
{
    __shared__ struct { unsigned short A2[2][128 * 64]; unsigned short B2[2][128 * 64]; } sh;
    const int tid = threadIdx.x, l = tid & 63, w = tid >> 6;
    const int b15 = l & 15, lg = l >> 4, x7 = b15 & 7;
    const int d = blockIdx.x;
    const int j = d >> 3;
    const int row0 = (j >> 2) * 128, e0 = ((d & 7) * 4 + (j & 3)) * 32;
    const int arow = w * 32 + b15;
    f32x4 acc[2][8] = {};

    auto stage = [&](int bf, int kt) {
        #pragma unroll
        for (int it = 0; it < 4; ++it) {
            const int slot = it * 256 + tid;
            const int row  = slot >> 3;
            const int chs  = (slot & 7) ^ (row & 7);
            const int kb   = (chs & 3) * 8;
            const unsigned short* sA = (chs & 4) ? g_xm   : g_xh;
            const unsigned short* sB = (chs & 4) ? g_Wihm : g_Wihh;
            const int ldsoff = bf * 16384 + slot * 16;
            const size_t aidx = (size_t)(row0 + row) * E_DIM + kt + kb;
            const int gt = row >> 5, er = row & 31;
            const size_t bidx = (size_t)(gt * E_DIM + e0 + er) * E_DIM + kt + kb;
            __builtin_amdgcn_global_load_lds(
                (const __attribute__((address_space(1))) void*)&sA[aidx],
                (__attribute__((address_space(3))) void*)((char*)sh.A2 + ldsoff), 16, 0, 0);
            __builtin_amdgcn_global_load_lds(
                (const __attribute__((address_space(1))) void*)&sB[bidx],
                (__attribute__((address_space(3))) void*)((char*)sh.B2 + ldsoff), 16, 0, 0);
        }
    };

    stage(0, 0);
    int cur = 0;
    for (int kt = 0; kt < E_DIM; kt += 32) {
        if (kt + 32 < E_DIM) {
            stage(cur ^ 1, kt + 32);
            asm volatile("s_waitcnt vmcnt(8)" ::: "memory");
        } else {
            asm volatile("s_waitcnt vmcnt(0)" ::: "memory");
        }
        __builtin_amdgcn_sched_barrier(0);
        __builtin_amdgcn_s_barrier();
        __builtin_amdgcn_sched_barrier(0);
        const unsigned short* Ab = sh.A2[cur];
        const unsigned short* Bb = sh.B2[cur];
        bf16x8 avh[2], avm[2];
        #pragma unroll
        for (int m = 0; m < 2; ++m) {
            const int rr = arow + m * 16;
            avh[m] = *reinterpret_cast<const bf16x8*>(&Ab[rr * 64 + ((lg ^ x7) * 8)]);
            avm[m] = *reinterpret_cast<const bf16x8*>(&Ab[rr * 64 + (((4 | lg) ^ x7) * 8)]);
        }
        #pragma unroll
        for (int n = 0; n < 8; ++n) {
            const int br = n * 16 + b15;
            const bf16x8 bvh = *reinterpret_cast<const bf16x8*>(&Bb[br * 64 + ((lg ^ x7) * 8)]);
            const bf16x8 bvm = *reinterpret_cast<const bf16x8*>(&Bb[br * 64 + (((4 | lg) ^ x7) * 8)]);
            #pragma unroll
            for (int m = 0; m < 2; ++m) {
                acc[m][n] = __builtin_amdgcn_mfma_f32_16x16x32_bf16(avh[m], bvm, acc[m][n], 0, 0, 0);
                acc[m][n] = __builtin_amdgcn_mfma_f32_16x16x32_bf16(avm[m], bvh, acc[m][n], 0, 0, 0);
                acc[m][n] = __builtin_amdgcn_mfma_f32_16x16x32_bf16(avh[m], bvh, acc[m][n], 0, 0, 0);
            }
        }
        __builtin_amdgcn_sched_barrier(0);
        __builtin_amdgcn_s_barrier();
        __builtin_amdgcn_sched_barrier(0);
        cur ^= 1;
    }

    const int rbase = row0 + w * 32 + lg * 4;
    #pragma unroll
    for (int m = 0; m < 2; ++m)
        #pragma unroll
        for (int n = 0; n < 8; ++n) {
            const int col = n * 16 + b15;
            const int gcol = (col >> 5) * E_DIM + e0 + (col & 31);
            const float add = bih[gcol] + bhh[gcol];
            #pragma unroll
            for (int q = 0; q < 4; ++q)
                __builtin_nontemporal_store(pack2(acc[m][n][q] + add),
                    &g_Gxp[(size_t)(rbase + m * 16 + q) * GATES_N + gcol]);
        }
}

// ---------------------------------------------------------------------------
// Merged step (round-10 proven structure; packed-Gx epilogue).
// Blocks 0..127: attention (32 rows, XCD-grouped by batch).
// Blocks 128..1151: GEMM+LSTM, BM=128 BN=128 BK=32, dbuf, counted vmcnt.
// ---------------------------------------------------------------------------
__global__ __launch_bounds__(256, 2) void step_kernel(
    const float* __restrict__ x, float* __restrict__ outp, const int step)
{
    __shared__ SharedU sh;
    const int tid = threadIdx.x, l = tid & 63, w = tid >> 6;
    const int b15 = l & 15, lg = l >> 4, x7 = b15 & 7;

    if (blockIdx.x < 128) {
        // ================= attention role =================
        if (step == 7) return;                          // final r is dead
        const int d = blockIdx.x;
        const int i = d >> 3;
        const int batch = (d & 7) * 4 + (i >> 2), chunk = i & 3;
        const int rowbase = batch * 128 + chunk * 32;
        const size_t sbase  = (size_t)batch * NKP * E_DIM;
        const size_t stbase = (size_t)batch * E_DIM * NKP;

        // --- QK^T: 3-split q x 3-split S, 6 terms. Wave w: j-cols w*80..+80 ---
        f32x4 qacc[2][5] = {};
        for (int kt = 0; kt < E_DIM; kt += 32) {
            bf16x8 qh[2], qm[2], ql[2];
            #pragma unroll
            for (int m = 0; m < 2; ++m) {
                const size_t qi = (size_t)(rowbase + m * 16 + b15) * E_DIM + kt + lg * 8;
                qh[m] = *reinterpret_cast<const bf16x8*>(&g_hinh[qi]);
                qm[m] = *reinterpret_cast<const bf16x8*>(&g_hinm[qi]);
                ql[m] = *reinterpret_cast<const bf16x8*>(&g_hinl[qi]);
            }
            #pragma unroll
            for (int n = 0; n < 5; ++n) {
                const size_t si = sbase + (size_t)(w * 80 + n * 16 + b15) * E_DIM + kt + lg * 8;
                const bf16x8 svh = *reinterpret_cast<const bf16x8*>(&g_Sh[si]);
                const bf16x8 svm = *reinterpret_cast<const bf16x8*>(&g_Sm[si]);
                const bf16x8 svl = *reinterpret_cast<const bf16x8*>(&g_Sl[si]);
                #pragma unroll
                for (int m = 0; m < 2; ++m) {
                    f32x4 a = qacc[m][n];
                    a = __builtin_amdgcn_mfma_f32_16x16x32_bf16(qh[m], svl, a, 0, 0, 0);
                    a = __builtin_amdgcn_mfma_f32_16x16x32_bf16(ql[m], svh, a, 0, 0, 0);
                    a = __builtin_amdgcn_mfma_f32_16x16x32_bf16(qm[m], svm, a, 0, 0, 0);
                    a = __builtin_amdgcn_mfma_f32_16x16x32_bf16(qh[m], svm, a, 0, 0, 0);
                    a = __builtin_amdgcn_mfma_f32_16x16x32_bf16(qm[m], svh, a, 0, 0, 0);
                    a = __builtin_amdgcn_mfma_f32_16x16x32_bf16(qh[m], svh, a, 0, 0, 0);
                    qacc[m][n] = a;
                }
            }
        }

        // --- softmax over 320 (row32 = m*16 + lg*4 + q, col j = w*80+n*16+b15) ---
        #pragma unroll
        for (int m = 0; m < 2; ++m)
            #pragma unroll
            for (int q = 0; q < 4; ++q) {
                float m0 = qacc[m][0][q];
                #pragma unroll
                for (int n = 1; n < 5; ++n) m0 = fmaxf(m0, qacc[m][n][q]);
                #pragma unroll
                for (int mk = 1; mk < 16; mk <<= 1) m0 = fmaxf(m0, __shfl_xor(m0, mk));
                if (b15 == 0) sh.a.red_m[w][m * 16 + lg * 4 + q] = m0;
            }
        __syncthreads();
        #pragma unroll
        for (int m = 0; m < 2; ++m)
            #pragma unroll
            for (int q = 0; q < 4; ++q) {
                const int row = m * 16 + lg * 4 + q;
                const float gm = fmaxf(fmaxf(sh.a.red_m[0][row], sh.a.red_m[1][row]),
                                       fmaxf(sh.a.red_m[2][row], sh.a.red_m[3][row]));
                float s = 0.f;
                #pragma unroll
                for (int n = 0; n < 5; ++n) {
                    const float e = __expf(qacc[m][n][q] - gm);
                    qacc[m][n][q] = e;
                    s += e;
                }
                #pragma unroll
                for (int mk = 1; mk < 16; mk <<= 1) s += __shfl_xor(s, mk);
                if (b15 == 0) sh.a.red_s[w][row] = s;
            }
        __syncthreads();
        #pragma unroll
        for (int m = 0; m < 2; ++m)
            #pragma unroll
            for (int q = 0; q < 4; ++q) {
                const int row = m * 16 + lg * 4 + q;
                const float inv = 1.f / (sh.a.red_s[0][row] + sh.a.red_s[1][row] +
                                         sh.a.red_s[2][row] + sh.a.red_s[3][row]);
                #pragma unroll
                for (int n = 0; n < 5; ++n) {
                    const float a = qacc[m][n][q] * inv;
                    unsigned short hi, mi;
                    split2(a, hi, mi);
                    const int col = w * 80 + n * 16 + b15;
                    sh.a.ah[row][col] = hi;
                    sh.a.am[row][col] = mi;
                }
            }
        __syncthreads();

        // --- PV: r = att @ S (via S^T), 2-split x 2-split, 3 terms ---
        #pragma unroll 1
        for (int pass = 0; pass < 4; ++pass) {
            const int ebase = w * 256 + pass * 64;
            f32x4 pacc[2][4] = {};
            for (int jt = 0; jt < NKP; jt += 32) {
                bf16x8 pah[2], pam[2];
                #pragma unroll
                for (int m = 0; m < 2; ++m) {
                    pah[m] = *reinterpret_cast<const bf16x8*>(&sh.a.ah[m * 16 + b15][jt + lg * 8]);
                    pam[m] = *reinterpret_cast<const bf16x8*>(&sh.a.am[m * 16 + b15][jt + lg * 8]);
                }
                #pragma unroll
                for (int n = 0; n < 4; ++n) {
                    const size_t sti = stbase + (size_t)(ebase + n * 16 + b15) * NKP + jt + lg * 8;
                    const bf16x8 sth = *reinterpret_cast<const bf16x8*>(&g_STh[sti]);
                    const bf16x8 stm = *reinterpret_cast<const bf16x8*>(&g_STm[sti]);
                    #pragma unroll
                    for (int m = 0; m < 2; ++m) {
                        f32x4 a = pacc[m][n];
                        a = __builtin_amdgcn_mfma_f32_16x16x32_bf16(pah[m], stm, a, 0, 0, 0);
                        a = __builtin_amdgcn_mfma_f32_16x16x32_bf16(pam[m], sth, a, 0, 0, 0);
                        a = __builtin_amdgcn_mfma_f32_16x16x32_bf16(pah[m], sth, a, 0, 0, 0);
                        pacc[m][n] = a;
                    }
                }
            }
            #pragma unroll
            for (int m = 0; m < 2; ++m)
                #pragma unroll
                for (int n = 0; n < 4; ++n)
                    #pragma unroll
                    for (int q = 0; q < 4; ++q)
                        __builtin_nontemporal_store(pacc[m][n][q],
                            &g_r[(size_t)(rowbase + m * 16 + lg * 4 + q) * E_DIM +
                                 ebase + n * 16 + b15]);
        }
        return;
    }

    // ================= GEMM + LSTM role =================
    const int d2 = blockIdx.x - 128;
    const int j = d2 >> 3;
    const int row0 = (j >> 2) * 128, e0 = ((d2 & 7) * 4 + (j & 3)) * 32;
    const int arow = w * 32 + b15;
    f32x4 acc[2][8] = {};

    auto stage = [&](int bf, int kt) {
        #pragma unroll
        for (int it = 0; it < 4; ++it) {
            const int slot = it * 256 + tid;
            const int row  = slot >> 3;
            const int chs  = (slot & 7) ^ (row & 7);
            const int kb   = (chs & 3) * 8;
            const unsigned short* sA = (chs & 4) ? g_hinm : g_hinh;
            const unsigned short* sB = (chs & 4) ? g_Whhm : g_Whhh;
            const int ldsoff = bf * 16384 + slot * 16;
            const size_t aidx = (size_t)(row0 + row) * E_DIM + kt + kb;
            const int gt = row >> 5, er = row & 31;
            const size_t bidx = (size_t)(gt * E_DIM + e0 + er) * E_DIM + kt + kb;
            __builtin_amdgcn_global_load_lds(
                (const __attribute__((address_space(1))) void*)&sA[aidx],
                (__attribute__((address_space(3))) void*)((char*)sh.g.A2 + ldsoff), 16, 0, 0);
            __builtin_amdgcn_global_load_lds(
                (const __attribute__((address_space(1))) void*)&sB[bidx],
                (__attribute__((address_space(3))) void*)((char*)sh.g.B2 + ldsoff), 16, 0, 0);
        }
    };

    stage(0, 0);
    int cur = 0;
    for (int kt = 0; kt < E_DIM; kt += 32) {
        if (kt + 32 < E_DIM) {
            stage(cur ^ 1, kt + 32);                       // 8 more in flight
            asm volatile("s_waitcnt vmcnt(8)" ::: "memory");
        } else {
            asm volatile("s_waitcnt vmcnt(0)" ::: "memory");
        }
        __builtin_amdgcn_sched_barrier(0);
        __builtin_amdgcn_s_barrier();                      // all waves: LDS ready
        __builtin_amdgcn_sched_barrier(0);
        const unsigned short* Ab = sh.g.A2[cur];
        const unsigned short* Bb = sh.g.B2[cur];
        bf16x8 avh[2], avm[2];
        #pragma unroll
        for (int m = 0; m < 2; ++m) {
            const int rr = arow + m * 16;
            avh[m] = *reinterpret_cast<const bf16x8*>(&Ab[rr * 64 + ((lg ^ x7) * 8)]);
            avm[m] = *reinterpret_cast<const bf16x8*>(&Ab[rr * 64 + (((4 | lg) ^ x7) * 8)]);
        }
        #pragma unroll
        for (int n = 0; n < 8; ++n) {
            const int br = n * 16 + b15;
            const bf16x8 bvh = *reinterpret_cast<const bf16x8*>(&Bb[br * 64 + ((lg ^ x7) * 8)]);
            const bf16x8 bvm = *reinterpret_cast<const bf16x8*>(&Bb[br * 64 + (((4 | lg) ^ x7) * 8)]);
            #pragma unroll
            for (int m = 0; m < 2; ++m) {
                acc[m][n] = __builtin_amdgcn_mfma_f32_16x16x32_bf16(avh[m], bvm, acc[m][n], 0, 0, 0);
                acc[m][n] = __builtin_amdgcn_mfma_f32_16x16x32_bf16(avm[m], bvh, acc[m][n], 0, 0, 0);
                acc[m][n] = __builtin_amdgcn_mfma_f32_16x16x32_bf16(avh[m], bvh, acc[m][n], 0, 0, 0);
            }
        }
        __builtin_amdgcn_sched_barrier(0);
        __builtin_amdgcn_s_barrier();                      // buf[cur] free to overwrite
        __builtin_amdgcn_sched_barrier(0);
        cur ^= 1;
    }

    const int rbase = row0 + w * 32 + lg * 4;
    const int do_out = (step == 7);
    #pragma unroll
    for (int m = 0; m < 2; ++m)
        #pragma unroll
        for (int er16 = 0; er16 < 2; ++er16) {
            const int e = e0 + er16 * 16 + b15;
            #pragma unroll
            for (int q = 0; q < 4; ++q) {
                const int row = rbase + m * 16 + q;
                const size_t gb = (size_t)row * GATES_N + e;
                const float gi = acc[m][0 + er16][q] + unpack2(__builtin_nontemporal_load(&g_Gxp[gb]));
                const float gf = acc[m][2 + er16][q] + unpack2(__builtin_nontemporal_load(&g_Gxp[gb + E_DIM]));
                const float gg = acc[m][4 + er16][q] + unpack2(__builtin_nontemporal_load(&g_Gxp[gb + 2 * E_DIM]));
                const float go = acc[m][6 + er16][q] + unpack2(__builtin_nontemporal_load(&g_Gxp[gb + 3 * E_DIM]));
                const size_t he = (size_t)row * E_DIM + e;
                const float cn = sigmoid_f(gf) * __builtin_nontemporal_load(&g_c[he]) +
                                 sigmoid_f(gi) * tanh_f(gg);
                const float hn = sigmoid_f(go) * tanh_f(cn) + x[he];
                if (do_out) {
                    __builtin_nontemporal_store(hn, &outp[he]);   // h/c dead after
                } else {
                    __builtin_nontemporal_store(cn, &g_c[he]);
                    g_h[he] = hn;
                }
            }
        }
}

extern "C" void kernel_launch(void* const* d_in, const int* in_sizes, int n_in,
                              void* d_out, int out_size, void* d_ws, size_t ws_size,
                              hipStream_t stream) {
    const float* x   = (const float*)d_in[0];
    const float* sup = (const float*)d_in[1];
    const float* Wih = (const float*)d_in[2];
    const float* Whh = (const float*)d_in[3];
    const float* bih = (const float*)d_in[4];
    const float* bhh = (const float*)d_in[5];
    float* out = (float*)d_out;

    prep_kernel<<<4096, 256, 0, stream>>>(Wih, Whh, x);
    split_S_kernel<<<dim3(16, 5, 32), 256, 0, stream>>>(sup);
    gemm_gx_kernel<<<1024, 256, 0, stream>>>(bih, bhh);
    meanS_kernel<<<128, 256, 0, stream>>>(sup);

    // step 0 is degenerate (zero carry): gates = Gx, attention exactly uniform.
    step0_kernel<<<4096, 256, 0, stream>>>(x);

    for (int s = 1; s < 8; ++s) {
        step_kernel<<<1152, 256, 0, stream>>>(x, out, s);
        if (s < 7) add_split3_kernel<<<4096, 256, 0, stream>>>();
    }
}